// Round 6
// baseline (10559.141 us; speedup 1.0000x reference)
//
#include <hip/hip_runtime.h>
#include <hip/hip_cooperative_groups.h>
#include <math.h>

namespace cg = cooperative_groups;

// Hierarchical RNN — round 6: bf16-packed fragment h-master (halves h traffic)
// + cooperative persistent encoder loops (grid.sync between steps, ping-pong
// row-major mirrors for the MFMA A-operand; Whh stays L2-hot per block).

#define NB     10272
#define MP     10368
#define ENC_   321
#define SEQ_   720
#define PRED_  96
#define BATCH_ 32

typedef long long i64;
typedef unsigned short u16;
typedef unsigned int u32;
using bf16x8 = __attribute__((ext_vector_type(8))) short;
using f32x4  = __attribute__((ext_vector_type(4))) float;

#define AS1 __attribute__((address_space(1)))
#define AS3 __attribute__((address_space(3)))
#define GLOAD16(g, l) __builtin_amdgcn_global_load_lds((const AS1 void*)(g), (AS3 void*)(l), 16, 0, 0)

__device__ __forceinline__ float bf2f(u16 u) {
    union { u32 i; float f; } v; v.i = ((u32)u) << 16; return v.f;
}
__device__ __forceinline__ u16 f2bf(float f) {
    union { float f; u32 i; } v; v.f = f;
    return (u16)((v.i + 0x7fff + ((v.i >> 16) & 1)) >> 16);
}
__device__ __forceinline__ float sigf(float x) {
    x = fminf(fmaxf(x, -30.f), 30.f);
    return 1.f / (1.f + __expf(-x));
}
__device__ __forceinline__ float tanhfast(float x) {
    x = fminf(fmaxf(x, -15.f), 15.f);
    float e = __expf(2.f * x);
    return (e - 1.f) / (e + 1.f);
}
__device__ __forceinline__ float bsel(uint2 u, int r) {
    u32 wv = (r & 2) ? u.y : u.x;
    return bf2f((u16)((r & 1) ? (wv >> 16) : (wv & 0xffff)));
}

// ---------------------------------------------------------------- small utils
__global__ __launch_bounds__(256) void zero_bf2(u16* __restrict__ a,
                                                u16* __restrict__ b, i64 n) {
    i64 i = (i64)blockIdx.x * 256 + threadIdx.x;
    if (i < n) { a[i] = 0; b[i] = 0; }
}

__global__ __launch_bounds__(256) void convert_pad(const float* __restrict__ src,
                                                   u16* __restrict__ dst,
                                                   int R, int C, int Rp, int Cp) {
    i64 idx = (i64)blockIdx.x * 256 + threadIdx.x;
    i64 total = (i64)Rp * Cp;
    if (idx >= total) return;
    int r = (int)(idx / Cp);
    int c = (int)(idx - (i64)r * Cp);
    dst[idx] = (r < R && c < C) ? f2bf(src[(i64)r * C + c]) : (u16)0;
}

__global__ __launch_bounds__(256) void seg_gather_bf(const float* __restrict__ x,
                                                     u16* __restrict__ dst,
                                                     int t0, int T, int s, int Kp) {
    i64 idx = (i64)blockIdx.x * 256 + threadIdx.x;
    i64 per_t = (i64)MP * Kp;
    i64 total = (i64)T * per_t;
    if (idx >= total) return;
    int t = (int)(idx / per_t);
    i64 rem = idx - (i64)t * per_t;
    int j = (int)(rem / MP);
    int n = (int)(rem - (i64)j * MP);
    float v = 0.f;
    if (n < NB && j < s) {
        int b = n / ENC_, e = n - b * ENC_;
        const float* xb = x + (i64)b * SEQ_ * ENC_ + e;
        v = xb[(i64)((t0 + t) * s + j) * ENC_] - xb[(i64)(SEQ_ - 1) * ENC_];
    }
    dst[((i64)t * MP + n) * Kp + j] = f2bf(v);
}

__global__ __launch_bounds__(256) void pmat_fill_bf(const float* __restrict__ pos,
                                                    const float* __restrict__ chan,
                                                    u16* __restrict__ dst,
                                                    int S, int d, int Rp) {
    i64 idx = (i64)blockIdx.x * 256 + threadIdx.x;
    i64 total = (i64)Rp * d;
    if (idx >= total) return;
    int row = (int)(idx / d);
    int c = (int)(idx - (i64)row * d);
    float v = 0.f;
    if (row < ENC_ * S) {
        int e = row / S, sy = row - e * S;
        int half = d >> 1;
        v = (c < half) ? pos[sy * half + c] : chan[e * half + (c - half)];
    }
    dst[idx] = f2bf(v);
}

__global__ __launch_bounds__(256) void out_kernel(const float* __restrict__ x,
                                                  const float* __restrict__ y0,
                                                  const float* __restrict__ y1,
                                                  float* __restrict__ out) {
    int idx = blockIdx.x * 256 + threadIdx.x;
    const int total = BATCH_ * PRED_ * ENC_;
    if (idx >= total) return;
    int b = idx / (PRED_ * ENC_);
    int r = idx - b * (PRED_ * ENC_);
    int p = r / ENC_;
    int e = r - p * ENC_;
    int n = b * ENC_ + e;
    float sl = x[(i64)b * SEQ_ * ENC_ + (i64)(SEQ_ - 1) * ENC_ + e];
    out[idx] = sl + 0.5f * (y0[(i64)n * PRED_ + p] + y1[(i64)n * PRED_ + p]);
}

// ------------------------------------------------- bf16 MFMA NT GEMM 128x128xK
// MODE: 0 fp32 natural, 1 bf16 natural, 2 bf16+relu, 3 fragment-packed
template<int MODE>
__global__ __launch_bounds__(256) void gemm_bf16mfma(const u16* __restrict__ A,
                                                     const u16* __restrict__ B,
                                                     const float* __restrict__ bias,
                                                     void* __restrict__ Cp,
                                                     int K, int Mstore, int Nstore,
                                                     int ldc, int dgate) {
    __shared__ u16 smA[128 * 64];
    __shared__ u16 smB[128 * 64];
    const int tid = threadIdx.x;
    const int w = tid >> 6, l = tid & 63;
    const int m0 = blockIdx.x * 128, n0 = blockIdx.y * 128;
    const int srow = (l >> 3) & 7, pch = l & 7;
    const int cch = pch ^ srow;
    const u16* ga[4]; const u16* gb[4];
#pragma unroll
    for (int r = 0; r < 4; ++r) {
        int seg = r * 4 + w;
        ga[r] = A + (i64)(m0 + seg * 8 + srow) * K + cch * 8;
        gb[r] = B + (i64)(n0 + seg * 8 + srow) * K + cch * 8;
    }
    f32x4 acc[4][4] = {};
    const int lr = l & 15, lg = l >> 4;
    const int wm = (w >> 1) * 64, wn = (w & 1) * 64;
    for (int kk = 0; kk < K; kk += 64) {
#pragma unroll
        for (int r = 0; r < 4; ++r) { GLOAD16(ga[r], smA + (r * 4 + w) * 512); ga[r] += 64; }
#pragma unroll
        for (int r = 0; r < 4; ++r) { GLOAD16(gb[r], smB + (r * 4 + w) * 512); gb[r] += 64; }
        __syncthreads();
#pragma unroll
        for (int s = 0; s < 2; ++s) {
            const int ph = ((s * 4 + lg) ^ (lr & 7)) * 8;
            bf16x8 av[4], bv[4];
#pragma unroll
            for (int i = 0; i < 4; ++i)
                av[i] = *(const bf16x8*)(smA + (wm + i * 16 + lr) * 64 + ph);
#pragma unroll
            for (int j = 0; j < 4; ++j)
                bv[j] = *(const bf16x8*)(smB + (wn + j * 16 + lr) * 64 + ph);
#pragma unroll
            for (int i = 0; i < 4; ++i)
#pragma unroll
                for (int j = 0; j < 4; ++j)
                    acc[i][j] = __builtin_amdgcn_mfma_f32_16x16x32_bf16(av[i], bv[j], acc[i][j], 0, 0, 0);
        }
        __syncthreads();
    }
#pragma unroll
    for (int i = 0; i < 4; ++i) {
        int mbase = m0 + wm + i * 16 + 4 * lg;
#pragma unroll
        for (int j = 0; j < 4; ++j) {
            int c = n0 + wn + j * 16 + lr;
            if (MODE == 3) {
                int NCT = dgate >> 4;
                int T = (m0 + wm + 16 * i) >> 4;
                int Cg = n0 + wn + 16 * j;
                int g = Cg / dgate;
                int ct = (Cg % dgate) >> 4;
                float bs = bias[c];
                u32 d0 = (u32)f2bf(acc[i][j][0] + bs) | ((u32)f2bf(acc[i][j][1] + bs) << 16);
                u32 d1 = (u32)f2bf(acc[i][j][2] + bs) | ((u32)f2bf(acc[i][j][3] + bs) << 16);
                ((uint2*)Cp)[((i64)(T * NCT + ct) * 3 + g) * 64 + l] = make_uint2(d0, d1);
            } else {
                if (c >= Nstore) continue;
                float bs = bias[c];
#pragma unroll
                for (int r = 0; r < 4; ++r) {
                    int mm = mbase + r;
                    if (mm < Mstore) {
                        float v = acc[i][j][r] + bs;
                        if (MODE == 2) v = fmaxf(v, 0.f);
                        if (MODE == 0) ((float*)Cp)[(i64)mm * ldc + c] = v;
                        else           ((u16*)Cp)[(i64)mm * ldc + c] = f2bf(v);
                    }
                }
            }
        }
    }
}

// ----------------- cooperative persistent encoder: gh GEMM + GRU per step
// grid (81, D/64); ping-pong mirrors (A-operand, row-major bf16); h master
// bf16-packed fragment layout (uint2/lane/tile), block-exclusive.
template<int D>
__global__ __launch_bounds__(256, (D == 512) ? 3 : 2)
void gru_coop(u16* __restrict__ mirA, u16* __restrict__ mirB,
              const u16* __restrict__ Whh, const float* __restrict__ bhh,
              const u16* __restrict__ gi, i64 gi_stride, int gi_mod,
              uint2* __restrict__ hmast, int t0, int nsteps) {
    constexpr int NCT = D / 16;
    __shared__ u16 smA[128 * 64];
    __shared__ u16 smB[3 * 64 * 64];
    cg::grid_group grid = cg::this_grid();
    const int tid = threadIdx.x;
    const int w = tid >> 6, l = tid & 63;
    const int m0 = blockIdx.x * 128;
    const int c0 = blockIdx.y * 64;
    const int srow = (l >> 3) & 7, pch = l & 7;
    const int cch = pch ^ srow;
    const int lr = l & 15, lg = l >> 4;
    const int wm = (w >> 1) * 64, wc = (w & 1) * 32;
    float bb[3][2];
#pragma unroll
    for (int j = 0; j < 2; ++j) {
        int cc = c0 + wc + 16 * j + lr;
        bb[0][j] = bhh[cc]; bb[1][j] = bhh[D + cc]; bb[2][j] = bhh[2 * D + cc];
    }
#pragma unroll 1
    for (int t = 0; t < nsteps; ++t) {
        const int tg = t0 + t;
        const u16* Asrc = (tg & 1) ? mirB : mirA;
        u16* Adst = (tg & 1) ? mirA : mirB;
        const u16* git = gi + (i64)(gi_mod ? (tg % gi_mod) : t) * gi_stride;
        const u16* ga[4]; const u16* gb[6];
#pragma unroll
        for (int r = 0; r < 4; ++r)
            ga[r] = Asrc + (i64)(m0 + (r * 4 + w) * 8 + srow) * D + cch * 8;
#pragma unroll
        for (int q = 0; q < 6; ++q) {
            int gs = q * 4 + w;
            int g = gs >> 3, sp = gs & 7;
            gb[q] = Whh + (i64)(g * D + c0 + sp * 8 + srow) * D + cch * 8;
        }
        f32x4 acc[3][4][2] = {};
        for (int kk = 0; kk < D; kk += 64) {
#pragma unroll
            for (int r = 0; r < 4; ++r) { GLOAD16(ga[r], smA + (r * 4 + w) * 512); ga[r] += 64; }
#pragma unroll
            for (int q = 0; q < 6; ++q) { GLOAD16(gb[q], smB + (q * 4 + w) * 512); gb[q] += 64; }
            __syncthreads();
#pragma unroll
            for (int s = 0; s < 2; ++s) {
                const int ph = ((s * 4 + lg) ^ (lr & 7)) * 8;
                bf16x8 av[4], bv[3][2];
#pragma unroll
                for (int i = 0; i < 4; ++i)
                    av[i] = *(const bf16x8*)(smA + (wm + i * 16 + lr) * 64 + ph);
#pragma unroll
                for (int g = 0; g < 3; ++g)
#pragma unroll
                    for (int j = 0; j < 2; ++j)
                        bv[g][j] = *(const bf16x8*)(smB + g * 4096 + (wc + j * 16 + lr) * 64 + ph);
#pragma unroll
                for (int g = 0; g < 3; ++g)
#pragma unroll
                    for (int i = 0; i < 4; ++i)
#pragma unroll
                        for (int j = 0; j < 2; ++j)
                            acc[g][i][j] = __builtin_amdgcn_mfma_f32_16x16x32_bf16(av[i], bv[g][j], acc[g][i][j], 0, 0, 0);
            }
            __syncthreads();
        }
#pragma unroll
        for (int i = 0; i < 4; ++i) {
            const int Trow = (m0 + wm + 16 * i) >> 4;
            const int rowb = m0 + wm + 16 * i + 4 * lg;
#pragma unroll
            for (int j = 0; j < 2; ++j) {
                const int cc = c0 + wc + 16 * j + lr;
                const int ct = (c0 + wc + 16 * j) >> 4;
                const i64 tb = (i64)Trow * NCT + ct;
                uint2 hou = hmast[tb * 64 + l];
                uint2 g0 = ((const uint2*)git)[(tb * 3 + 0) * 64 + l];
                uint2 g1 = ((const uint2*)git)[(tb * 3 + 1) * 64 + l];
                uint2 g2 = ((const uint2*)git)[(tb * 3 + 2) * 64 + l];
                u16 hb[4];
#pragma unroll
                for (int r = 0; r < 4; ++r) {
                    float rr = sigf(bsel(g0, r) + acc[0][i][j][r] + bb[0][j]);
                    float zz = sigf(bsel(g1, r) + acc[1][i][j][r] + bb[1][j]);
                    float nn = tanhfast(bsel(g2, r) + rr * (acc[2][i][j][r] + bb[2][j]));
                    hb[r] = f2bf((1.f - zz) * nn + zz * bsel(hou, r));
                }
                hmast[tb * 64 + l] = make_uint2((u32)hb[0] | ((u32)hb[1] << 16),
                                                (u32)hb[2] | ((u32)hb[3] << 16));
#pragma unroll
                for (int r = 0; r < 4; ++r)
                    Adst[(i64)(rowb + r) * D + cc] = hb[r];
            }
        }
        __threadfence();
        grid.sync();
    }
}

// ---------------------------------------- decoder: fused gh-GEMM + GRU (S>0)
template<int D, int S>
__global__ __launch_bounds__(256) void gru_dec(const u16* __restrict__ Abf,
                                               const u16* __restrict__ Whh,
                                               const float* __restrict__ bhh,
                                               const u16* __restrict__ gi,
                                               const uint2* __restrict__ hmast,
                                               u16* __restrict__ hy) {
    constexpr int NCT = D / 16;
    __shared__ u16 smA[128 * 64];
    __shared__ u16 smB[3 * 64 * 64];
    const int tid = threadIdx.x;
    const int w = tid >> 6, l = tid & 63;
    const int m0 = blockIdx.x * 128;
    const int c0 = blockIdx.y * 64;
    const int srow = (l >> 3) & 7, pch = l & 7;
    const int cch = pch ^ srow;
    const u16* ga[4]; const u16* gb[6];
#pragma unroll
    for (int r = 0; r < 4; ++r)
        ga[r] = Abf + (i64)(m0 + (r * 4 + w) * 8 + srow) * D + cch * 8;
#pragma unroll
    for (int q = 0; q < 6; ++q) {
        int gs = q * 4 + w;
        int g = gs >> 3, sp = gs & 7;
        gb[q] = Whh + (i64)(g * D + c0 + sp * 8 + srow) * D + cch * 8;
    }
    f32x4 acc[3][4][2] = {};
    const int lr = l & 15, lg = l >> 4;
    const int wm = (w >> 1) * 64, wc = (w & 1) * 32;
    for (int kk = 0; kk < D; kk += 64) {
#pragma unroll
        for (int r = 0; r < 4; ++r) { GLOAD16(ga[r], smA + (r * 4 + w) * 512); ga[r] += 64; }
#pragma unroll
        for (int q = 0; q < 6; ++q) { GLOAD16(gb[q], smB + (q * 4 + w) * 512); gb[q] += 64; }
        __syncthreads();
#pragma unroll
        for (int s = 0; s < 2; ++s) {
            const int ph = ((s * 4 + lg) ^ (lr & 7)) * 8;
            bf16x8 av[4], bv[3][2];
#pragma unroll
            for (int i = 0; i < 4; ++i)
                av[i] = *(const bf16x8*)(smA + (wm + i * 16 + lr) * 64 + ph);
#pragma unroll
            for (int g = 0; g < 3; ++g)
#pragma unroll
                for (int j = 0; j < 2; ++j)
                    bv[g][j] = *(const bf16x8*)(smB + g * 4096 + (wc + j * 16 + lr) * 64 + ph);
#pragma unroll
            for (int g = 0; g < 3; ++g)
#pragma unroll
                for (int i = 0; i < 4; ++i)
#pragma unroll
                    for (int j = 0; j < 2; ++j)
                        acc[g][i][j] = __builtin_amdgcn_mfma_f32_16x16x32_bf16(av[i], bv[g][j], acc[g][i][j], 0, 0, 0);
        }
        __syncthreads();
    }
#pragma unroll
    for (int i = 0; i < 4; ++i) {
        const int Trow = (m0 + wm + 16 * i) >> 4;
        const int rowb = m0 + wm + 16 * i + 4 * lg;
#pragma unroll
        for (int j = 0; j < 2; ++j) {
            const int cc = c0 + wc + 16 * j + lr;
            const int ct = (c0 + wc + 16 * j) >> 4;
            const i64 tb = (i64)Trow * NCT + ct;
            float b0 = bhh[cc], b1 = bhh[D + cc], b2 = bhh[2 * D + cc];
            uint2 hou = hmast[tb * 64 + l];
#pragma unroll
            for (int r = 0; r < 4; ++r) {
                int mm = rowb + r;
                if (mm >= NB) continue;
                int e = mm % ENC_;
                float hr = acc[0][i][j][r] + b0;
                float hz = acc[1][i][j][r] + b1;
                float hn2 = acc[2][i][j][r] + b2;
                float ho = bsel(hou, r);
#pragma unroll
                for (int sy = 0; sy < S; ++sy) {
                    i64 gib = (i64)(e * S + sy) * 3 * D + cc;
                    float rr = sigf(bf2f(gi[gib]) + hr);
                    float zz = sigf(bf2f(gi[gib + D]) + hz);
                    float nn = tanhfast(bf2f(gi[gib + 2 * D]) + rr * hn2);
                    hy[((i64)mm * S + sy) * D + cc] = f2bf((1.f - zz) * nn + zz * ho);
                }
            }
        }
    }
}

// ---------------------------------------------------------------- host
extern "C" void kernel_launch(void* const* d_in, const int* in_sizes, int n_in,
                              void* d_out, int out_size, void* d_ws, size_t ws_size,
                              hipStream_t stream) {
    const float* x      = (const float*)d_in[0];
    const float* W_emb0 = (const float*)d_in[1];
    const float* b_emb0 = (const float*)d_in[2];
    const float* Wih0   = (const float*)d_in[3];
    const float* Whh0   = (const float*)d_in[4];
    const float* bih0   = (const float*)d_in[5];
    const float* bhh0   = (const float*)d_in[6];
    const float* Wpred0 = (const float*)d_in[7];
    const float* bpred0 = (const float*)d_in[8];
    const float* pos0   = (const float*)d_in[9];
    const float* chan0  = (const float*)d_in[10];
    const float* W_emb1 = (const float*)d_in[11];
    const float* b_emb1 = (const float*)d_in[12];
    const float* Wih1   = (const float*)d_in[13];
    const float* Whh1   = (const float*)d_in[14];
    const float* bih1   = (const float*)d_in[15];
    const float* bhh1   = (const float*)d_in[16];
    const float* Wpred1 = (const float*)d_in[17];
    const float* bpred1 = (const float*)d_in[18];
    const float* pos1   = (const float*)d_in[19];
    const float* chan1  = (const float*)d_in[20];
    float* out = (float*)d_out;

    i64 off = 0;
    char* base = (char*)d_ws;
    auto alloc = [&](i64 bytes) -> void* {
        void* p = base + off; off += (bytes + 255) & ~(i64)255; return p;
    };
    u16*   f_hm    = (u16*)  alloc((i64)MP * 512 * 2);   // bf16-packed fragment master
    u16*   f_mirA  = (u16*)  alloc((i64)MP * 512 * 2);   // ping-pong row-major mirrors
    u16*   f_mirB  = (u16*)  alloc((i64)MP * 512 * 2);
    u16*   wih0b   = (u16*)  alloc((i64)1536 * 512 * 2);
    u16*   whh0b   = (u16*)  alloc((i64)1536 * 512 * 2);
    u16*   wih1b   = (u16*)  alloc((i64)768 * 256 * 2);
    u16*   whh1b   = (u16*)  alloc((i64)768 * 256 * 2);
    u16*   we0b    = (u16*)  alloc((i64)512 * 64 * 2);
    u16*   we1b    = (u16*)  alloc((i64)256 * 64 * 2);
    u16*   wp0b    = (u16*)  alloc((i64)128 * 512 * 2);
    u16*   wp1b    = (u16*)  alloc((i64)128 * 256 * 2);
    u16*   f_pm0   = (u16*)  alloc((i64)768 * 512 * 2);
    u16*   f_pm1   = (u16*)  alloc((i64)1408 * 256 * 2);
    u16*   f_gidec = (u16*)  alloc((i64)768 * 1536 * 2);
    float* f_y0    = (float*)alloc((i64)NB * 96 * 4);
    float* f_y1    = (float*)alloc((i64)NB * 96 * 4);
    i64 fixed = off;

    char* R = base + fixed;
    i64 a1 = (((i64)4 * MP * 64 * 2) + 255) & ~(i64)255;
    i64 a2 = (((i64)4 * MP * 256 * 2) + 255) & ~(i64)255;
    i64 a3 = (i64)4 * MP * 768 * 2;
    i64 R1 = a1 + a2 + a3;
    u16* f_seg1 = (u16*)R;
    u16* f_xe1  = (u16*)(R + a1);
    u16* f_gi1  = (u16*)(R + a1 + a2);   // fragment-packed, 4 segments
    u16* f_hy   = f_gi1;                  // alias (decoders run after gi use)
    int gsz = 2;
    {
        const int cand[3] = {15, 5, 3};
        for (int ii = 0; ii < 3; ++ii) {
            i64 need = (i64)cand[ii] * MP * (64 + 512 + 1536) * 2 + 3 * 256;
            i64 tot = fixed + (need > R1 ? need : R1);
            if (tot <= (i64)ws_size) { gsz = cand[ii]; break; }
        }
    }
    u16* f_seg0 = (u16*)R;
    i64 s1 = (((i64)gsz * MP * 64 * 2) + 255) & ~(i64)255;
    i64 s2 = (((i64)gsz * MP * 512 * 2) + 255) & ~(i64)255;
    u16* f_xe0 = (u16*)(R + s1);
    u16* f_gi0 = (u16*)(R + s1 + s2);    // fragment-packed, gsz steps

    auto cvt = [&](const float* s, u16* dst, int Rr, int C, int Rp, int Cp) {
        i64 tot = (i64)Rp * Cp;
        convert_pad<<<(int)((tot + 255) / 256), 256, 0, stream>>>(s, dst, Rr, C, Rp, Cp);
    };
    auto gemmN = [&](const u16* A, const u16* B, const float* bias, void* C,
                     int gx, int Nc, int K, int Mstore, int ldc, int mode, int dgate) {
        dim3 g(gx, (Nc + 127) / 128);
        if (mode == 0)      gemm_bf16mfma<0><<<g, 256, 0, stream>>>(A, B, bias, C, K, Mstore, Nc, ldc, dgate);
        else if (mode == 1) gemm_bf16mfma<1><<<g, 256, 0, stream>>>(A, B, bias, C, K, Mstore, Nc, ldc, dgate);
        else if (mode == 2) gemm_bf16mfma<2><<<g, 256, 0, stream>>>(A, B, bias, C, K, Mstore, Nc, ldc, dgate);
        else                gemm_bf16mfma<3><<<g, 256, 0, stream>>>(A, B, bias, C, K, Mstore, Nc, ldc, dgate);
    };

    cvt(Wih0, wih0b, 1536, 512, 1536, 512);
    cvt(Whh0, whh0b, 1536, 512, 1536, 512);
    cvt(Wih1, wih1b, 768, 256, 768, 256);
    cvt(Whh1, whh1b, 768, 256, 768, 256);
    cvt(W_emb0, we0b, 512, 48, 512, 64);
    cvt(W_emb1, we1b, 256, 24, 256, 64);
    cvt(Wpred0, wp0b, 48, 512, 128, 512);
    cvt(Wpred1, wp1b, 24, 256, 128, 256);
    pmat_fill_bf<<<(int)(((i64)768 * 512 + 255) / 256), 256, 0, stream>>>(pos0, chan0, f_pm0, 2, 512, 768);
    pmat_fill_bf<<<(int)(((i64)1408 * 256 + 255) / 256), 256, 0, stream>>>(pos1, chan1, f_pm1, 4, 256, 1408);

    // ================= layer 0: d=512, 15 steps in coop groups of gsz =========
    {
        i64 n = (i64)MP * 512;
        zero_bf2<<<(int)((n + 255) / 256), 256, 0, stream>>>(f_hm, f_mirA, n);
    }
    for (int t0 = 0; t0 < 15;) {
        int g = 15 - t0 < gsz ? 15 - t0 : gsz;
        i64 tot = (i64)g * MP * 64;
        seg_gather_bf<<<(int)((tot + 255) / 256), 256, 0, stream>>>(x, f_seg0, t0, g, 48, 64);
        gemmN(f_seg0, we0b, b_emb0, f_xe0, g * 81, 512, 64, g * MP, 512, 2, 0);
        gemmN(f_xe0, wih0b, bih0, f_gi0, g * 81, 1536, 512, 0, 0, 3, 512);
        {
            u16* p0 = f_mirA; u16* p1 = f_mirB;
            const u16* p2 = whh0b; const float* p3 = bhh0;
            const u16* p4 = f_gi0; i64 p5 = (i64)MP * 1536; int p6 = 0;
            uint2* p7 = (uint2*)f_hm; int p8 = t0; int p9 = g;
            void* ka[10] = {&p0, &p1, &p2, &p3, &p4, &p5, &p6, &p7, &p8, &p9};
            hipLaunchCooperativeKernel((const void*)gru_coop<512>, dim3(81, 8),
                                       dim3(256), ka, 0, stream);
        }
        t0 += g;
    }
    // decoder 0 (15 steps -> final mirror = B)
    gemmN(f_pm0, wih0b, bih0, f_gidec, 6, 1536, 512, 642, 1536, 1, 0);
    gru_dec<512, 2><<<dim3(81, 8), 256, 0, stream>>>(f_mirB, whh0b, bhh0, f_gidec,
                                                     (const uint2*)f_hm, f_hy);
    gemmN(f_hy, wp0b, bpred0, f_y0, 161, 48, 512, 2 * NB, 48, 0, 0);

    // ================= layer 1: d=256, 60 steps, ONE cooperative launch =======
    {
        i64 n = (i64)MP * 256;
        zero_bf2<<<(int)((n + 255) / 256), 256, 0, stream>>>(f_hm, f_mirA, n);
    }
    {
        i64 tot = (i64)4 * MP * 64;
        seg_gather_bf<<<(int)((tot + 255) / 256), 256, 0, stream>>>(x, f_seg1, 0, 4, 24, 64);
    }
    gemmN(f_seg1, we1b, b_emb1, f_xe1, 324, 256, 64, 4 * MP, 256, 2, 0);
    gemmN(f_xe1, wih1b, bih1, f_gi1, 324, 768, 256, 0, 0, 3, 256);
    {
        u16* p0 = f_mirA; u16* p1 = f_mirB;
        const u16* p2 = whh1b; const float* p3 = bhh1;
        const u16* p4 = f_gi1; i64 p5 = (i64)MP * 768; int p6 = 4;
        uint2* p7 = (uint2*)f_hm; int p8 = 0; int p9 = 60;
        void* ka[10] = {&p0, &p1, &p2, &p3, &p4, &p5, &p6, &p7, &p8, &p9};
        hipLaunchCooperativeKernel((const void*)gru_coop<256>, dim3(81, 4),
                                   dim3(256), ka, 0, stream);
    }
    // decoder 1 (60 steps -> final mirror = A)
    gemmN(f_pm1, wih1b, bih1, f_gidec, 11, 768, 256, 1284, 768, 1, 0);
    gru_dec<256, 4><<<dim3(81, 4), 256, 0, stream>>>(f_mirA, whh1b, bhh1, f_gidec,
                                                     (const uint2*)f_hm, f_hy);
    gemmN(f_hy, wp1b, bpred1, f_y1, 321, 24, 256, 4 * NB, 24, 0, 0);

    // ================= combine =================
    out_kernel<<<(BATCH_ * PRED_ * ENC_ + 255) / 256, 256, 0, stream>>>(x, f_y0, f_y1, out);
}

// Round 7
// 2897.402 us; speedup vs baseline: 3.6443x; 3.6443x over previous
//
#include <hip/hip_runtime.h>
#include <math.h>

// Hierarchical RNN — round 7: R5 structure (per-step fused gh-GEMM+GRU,
// fragment-packed gi, fp32 fragment h-master) + ping-pong A-mirrors (fixes
// R5's latent same-buffer race) + flat-grid XCD-aware swizzle so each XCD
// keeps one A-tile L2-resident across its N-sweep (cuts L2-fill refetch).

#define NB     10272
#define MP     10368
#define ENC_   321
#define SEQ_   720
#define PRED_  96
#define BATCH_ 32

typedef long long i64;
typedef unsigned short u16;
typedef unsigned int u32;
using bf16x8 = __attribute__((ext_vector_type(8))) short;
using f32x4  = __attribute__((ext_vector_type(4))) float;

#define AS1 __attribute__((address_space(1)))
#define AS3 __attribute__((address_space(3)))
#define GLOAD16(g, l) __builtin_amdgcn_global_load_lds((const AS1 void*)(g), (AS3 void*)(l), 16, 0, 0)

__device__ __forceinline__ float bf2f(u16 u) {
    union { u32 i; float f; } v; v.i = ((u32)u) << 16; return v.f;
}
__device__ __forceinline__ u16 f2bf(float f) {
    union { float f; u32 i; } v; v.f = f;
    return (u16)((v.i + 0x7fff + ((v.i >> 16) & 1)) >> 16);
}
__device__ __forceinline__ float sigf(float x) {
    x = fminf(fmaxf(x, -30.f), 30.f);
    return 1.f / (1.f + __expf(-x));
}
__device__ __forceinline__ float tanhfast(float x) {
    x = fminf(fmaxf(x, -15.f), 15.f);
    float e = __expf(2.f * x);
    return (e - 1.f) / (e + 1.f);
}
__device__ __forceinline__ float bsel(uint2 u, int r) {
    u32 wv = (r & 2) ? u.y : u.x;
    return bf2f((u16)((r & 1) ? (wv >> 16) : (wv & 0xffff)));
}
// XCD-aware flat-grid swizzle: groups of 8 m-tiles; within a group, idx%8
// picks the m-tile (-> XCD via round-robin), idx/8 sweeps n-tiles. Each XCD
// sees one A-tile for NYT consecutive blocks -> A stays in its L2.
__device__ __forceinline__ void swz(int idx, int NXT, int NYT, int& mt, int& nt) {
    int per = NYT * 8;
    int grp = idx / per;
    int base = grp * 8;
    int mg = NXT - base; if (mg > 8) mg = 8;
    int rem = idx - grp * per;
    mt = base + rem % mg;
    nt = rem / mg;
}

// ---------------------------------------------------------------- small utils
__global__ __launch_bounds__(256) void zero2_kernel(float* __restrict__ a,
                                                    u16* __restrict__ b, i64 n) {
    i64 i = (i64)blockIdx.x * 256 + threadIdx.x;
    if (i < n) { a[i] = 0.f; b[i] = 0; }
}

__global__ __launch_bounds__(256) void convert_pad(const float* __restrict__ src,
                                                   u16* __restrict__ dst,
                                                   int R, int C, int Rp, int Cp) {
    i64 idx = (i64)blockIdx.x * 256 + threadIdx.x;
    i64 total = (i64)Rp * Cp;
    if (idx >= total) return;
    int r = (int)(idx / Cp);
    int c = (int)(idx - (i64)r * Cp);
    dst[idx] = (r < R && c < C) ? f2bf(src[(i64)r * C + c]) : (u16)0;
}

__global__ __launch_bounds__(256) void seg_gather_bf(const float* __restrict__ x,
                                                     u16* __restrict__ dst,
                                                     int t0, int T, int s, int Kp) {
    i64 idx = (i64)blockIdx.x * 256 + threadIdx.x;
    i64 per_t = (i64)MP * Kp;
    i64 total = (i64)T * per_t;
    if (idx >= total) return;
    int t = (int)(idx / per_t);
    i64 rem = idx - (i64)t * per_t;
    int j = (int)(rem / MP);
    int n = (int)(rem - (i64)j * MP);
    float v = 0.f;
    if (n < NB && j < s) {
        int b = n / ENC_, e = n - b * ENC_;
        const float* xb = x + (i64)b * SEQ_ * ENC_ + e;
        v = xb[(i64)((t0 + t) * s + j) * ENC_] - xb[(i64)(SEQ_ - 1) * ENC_];
    }
    dst[((i64)t * MP + n) * Kp + j] = f2bf(v);
}

__global__ __launch_bounds__(256) void pmat_fill_bf(const float* __restrict__ pos,
                                                    const float* __restrict__ chan,
                                                    u16* __restrict__ dst,
                                                    int S, int d, int Rp) {
    i64 idx = (i64)blockIdx.x * 256 + threadIdx.x;
    i64 total = (i64)Rp * d;
    if (idx >= total) return;
    int row = (int)(idx / d);
    int c = (int)(idx - (i64)row * d);
    float v = 0.f;
    if (row < ENC_ * S) {
        int e = row / S, sy = row - e * S;
        int half = d >> 1;
        v = (c < half) ? pos[sy * half + c] : chan[e * half + (c - half)];
    }
    dst[idx] = f2bf(v);
}

__global__ __launch_bounds__(256) void out_kernel(const float* __restrict__ x,
                                                  const float* __restrict__ y0,
                                                  const float* __restrict__ y1,
                                                  float* __restrict__ out) {
    int idx = blockIdx.x * 256 + threadIdx.x;
    const int total = BATCH_ * PRED_ * ENC_;
    if (idx >= total) return;
    int b = idx / (PRED_ * ENC_);
    int r = idx - b * (PRED_ * ENC_);
    int p = r / ENC_;
    int e = r - p * ENC_;
    int n = b * ENC_ + e;
    float sl = x[(i64)b * SEQ_ * ENC_ + (i64)(SEQ_ - 1) * ENC_ + e];
    out[idx] = sl + 0.5f * (y0[(i64)n * PRED_ + p] + y1[(i64)n * PRED_ + p]);
}

// ------------------------------------------------- bf16 MFMA NT GEMM 128x128xK
// Flat grid NXT*NYT with swz(). MODE: 0 fp32, 1 bf16, 2 bf16+relu, 3 frag-packed.
template<int MODE>
__global__ __launch_bounds__(256) void gemm_bf16mfma(const u16* __restrict__ A,
                                                     const u16* __restrict__ B,
                                                     const float* __restrict__ bias,
                                                     void* __restrict__ Cp,
                                                     int K, int Mstore, int Nstore,
                                                     int ldc, int dgate,
                                                     int NXT, int NYT) {
    __shared__ u16 smA[128 * 64];
    __shared__ u16 smB[128 * 64];
    const int tid = threadIdx.x;
    const int w = tid >> 6, l = tid & 63;
    int mt, nt; swz(blockIdx.x, NXT, NYT, mt, nt);
    const int m0 = mt * 128, n0 = nt * 128;
    const int srow = (l >> 3) & 7, pch = l & 7;
    const int cch = pch ^ srow;
    const u16* ga[4]; const u16* gb[4];
#pragma unroll
    for (int r = 0; r < 4; ++r) {
        int seg = r * 4 + w;
        ga[r] = A + (i64)(m0 + seg * 8 + srow) * K + cch * 8;
        gb[r] = B + (i64)(n0 + seg * 8 + srow) * K + cch * 8;
    }
    f32x4 acc[4][4] = {};
    const int lr = l & 15, lg = l >> 4;
    const int wm = (w >> 1) * 64, wn = (w & 1) * 64;
    for (int kk = 0; kk < K; kk += 64) {
#pragma unroll
        for (int r = 0; r < 4; ++r) { GLOAD16(ga[r], smA + (r * 4 + w) * 512); ga[r] += 64; }
#pragma unroll
        for (int r = 0; r < 4; ++r) { GLOAD16(gb[r], smB + (r * 4 + w) * 512); gb[r] += 64; }
        __syncthreads();
#pragma unroll
        for (int s = 0; s < 2; ++s) {
            const int ph = ((s * 4 + lg) ^ (lr & 7)) * 8;
            bf16x8 av[4], bv[4];
#pragma unroll
            for (int i = 0; i < 4; ++i)
                av[i] = *(const bf16x8*)(smA + (wm + i * 16 + lr) * 64 + ph);
#pragma unroll
            for (int j = 0; j < 4; ++j)
                bv[j] = *(const bf16x8*)(smB + (wn + j * 16 + lr) * 64 + ph);
#pragma unroll
            for (int i = 0; i < 4; ++i)
#pragma unroll
                for (int j = 0; j < 4; ++j)
                    acc[i][j] = __builtin_amdgcn_mfma_f32_16x16x32_bf16(av[i], bv[j], acc[i][j], 0, 0, 0);
        }
        __syncthreads();
    }
#pragma unroll
    for (int i = 0; i < 4; ++i) {
        int mbase = m0 + wm + i * 16 + 4 * lg;
#pragma unroll
        for (int j = 0; j < 4; ++j) {
            int c = n0 + wn + j * 16 + lr;
            if (MODE == 3) {
                int NCT = dgate >> 4;
                int T = (m0 + wm + 16 * i) >> 4;
                int Cg = n0 + wn + 16 * j;
                int g = Cg / dgate;
                int ct = (Cg % dgate) >> 4;
                float bs = bias[c];
                u32 d0 = (u32)f2bf(acc[i][j][0] + bs) | ((u32)f2bf(acc[i][j][1] + bs) << 16);
                u32 d1 = (u32)f2bf(acc[i][j][2] + bs) | ((u32)f2bf(acc[i][j][3] + bs) << 16);
                ((uint2*)Cp)[((i64)(T * NCT + ct) * 3 + g) * 64 + l] = make_uint2(d0, d1);
            } else {
                if (c >= Nstore) continue;
                float bs = bias[c];
#pragma unroll
                for (int r = 0; r < 4; ++r) {
                    int mm = mbase + r;
                    if (mm < Mstore) {
                        float v = acc[i][j][r] + bs;
                        if (MODE == 2) v = fmaxf(v, 0.f);
                        if (MODE == 0) ((float*)Cp)[(i64)mm * ldc + c] = v;
                        else           ((u16*)Cp)[(i64)mm * ldc + c] = f2bf(v);
                    }
                }
            }
        }
    }
}

// --------------------------- fused gh-GEMM + GRU pointwise (per step)
// S==0 encoder: reads Asrc mirror (prev h, row-major bf16), gi fragment-packed,
//   h fp32 fragment master r/w, writes new h to Adst mirror (ping-pong, no race).
// S>0 decoder: Asrc = final mirror, gi_dec natural, writes hy bf16 row-major.
template<int D, int S>
__global__ __launch_bounds__(256) void gru_fused_v2(const u16* __restrict__ Asrc,
                                                    const u16* __restrict__ Whh,
                                                    const float* __restrict__ bhh,
                                                    const u16* __restrict__ gi,
                                                    f32x4* __restrict__ hfrag,
                                                    u16* __restrict__ Adst,
                                                    u16* __restrict__ hy) {
    constexpr int NCT = D / 16;
    constexpr int NYT = D / 64;
    __shared__ u16 smA[128 * 64];
    __shared__ u16 smB[3 * 64 * 64];
    const int tid = threadIdx.x;
    const int w = tid >> 6, l = tid & 63;
    int mt, nt; swz(blockIdx.x, 81, NYT, mt, nt);
    const int m0 = mt * 128;
    const int c0 = nt * 64;
    const int srow = (l >> 3) & 7, pch = l & 7;
    const int cch = pch ^ srow;
    const u16* ga[4]; const u16* gb[6];
#pragma unroll
    for (int r = 0; r < 4; ++r)
        ga[r] = Asrc + (i64)(m0 + (r * 4 + w) * 8 + srow) * D + cch * 8;
#pragma unroll
    for (int q = 0; q < 6; ++q) {
        int gs = q * 4 + w;
        int g = gs >> 3, sp = gs & 7;
        gb[q] = Whh + (i64)(g * D + c0 + sp * 8 + srow) * D + cch * 8;
    }
    f32x4 acc[3][4][2] = {};
    const int lr = l & 15, lg = l >> 4;
    const int wm = (w >> 1) * 64, wc = (w & 1) * 32;
    for (int kk = 0; kk < D; kk += 64) {
#pragma unroll
        for (int r = 0; r < 4; ++r) { GLOAD16(ga[r], smA + (r * 4 + w) * 512); ga[r] += 64; }
#pragma unroll
        for (int q = 0; q < 6; ++q) { GLOAD16(gb[q], smB + (q * 4 + w) * 512); gb[q] += 64; }
        __syncthreads();
#pragma unroll
        for (int s = 0; s < 2; ++s) {
            const int ph = ((s * 4 + lg) ^ (lr & 7)) * 8;
            bf16x8 av[4], bv[3][2];
#pragma unroll
            for (int i = 0; i < 4; ++i)
                av[i] = *(const bf16x8*)(smA + (wm + i * 16 + lr) * 64 + ph);
#pragma unroll
            for (int g = 0; g < 3; ++g)
#pragma unroll
                for (int j = 0; j < 2; ++j)
                    bv[g][j] = *(const bf16x8*)(smB + g * 4096 + (wc + j * 16 + lr) * 64 + ph);
#pragma unroll
            for (int g = 0; g < 3; ++g)
#pragma unroll
                for (int i = 0; i < 4; ++i)
#pragma unroll
                    for (int j = 0; j < 2; ++j)
                        acc[g][i][j] = __builtin_amdgcn_mfma_f32_16x16x32_bf16(av[i], bv[g][j], acc[g][i][j], 0, 0, 0);
        }
        __syncthreads();
    }
#pragma unroll
    for (int i = 0; i < 4; ++i) {
        const int Trow = (m0 + wm + 16 * i) >> 4;
        const int rowb = m0 + wm + 16 * i + 4 * lg;
#pragma unroll
        for (int j = 0; j < 2; ++j) {
            const int cc = c0 + wc + 16 * j + lr;
            const int ct = (c0 + wc + 16 * j) >> 4;
            const i64 tb = (i64)Trow * NCT + ct;
            float b0 = bhh[cc], b1 = bhh[D + cc], b2 = bhh[2 * D + cc];
            f32x4 ho = hfrag[tb * 64 + l];
            if constexpr (S == 0) {
                uint2 g0 = ((const uint2*)gi)[(tb * 3 + 0) * 64 + l];
                uint2 g1 = ((const uint2*)gi)[(tb * 3 + 1) * 64 + l];
                uint2 g2 = ((const uint2*)gi)[(tb * 3 + 2) * 64 + l];
                f32x4 hn_;
#pragma unroll
                for (int r = 0; r < 4; ++r) {
                    float rr = sigf(bsel(g0, r) + acc[0][i][j][r] + b0);
                    float zz = sigf(bsel(g1, r) + acc[1][i][j][r] + b1);
                    float nn = tanhfast(bsel(g2, r) + rr * (acc[2][i][j][r] + b2));
                    hn_[r] = (1.f - zz) * nn + zz * ho[r];
                }
                hfrag[tb * 64 + l] = hn_;
#pragma unroll
                for (int r = 0; r < 4; ++r)
                    Adst[(i64)(rowb + r) * D + cc] = f2bf(hn_[r]);
            } else {
#pragma unroll
                for (int r = 0; r < 4; ++r) {
                    int mm = rowb + r;
                    if (mm >= NB) continue;
                    int e = mm % ENC_;
                    float hr = acc[0][i][j][r] + b0;
                    float hz = acc[1][i][j][r] + b1;
                    float hn2 = acc[2][i][j][r] + b2;
#pragma unroll
                    for (int sy = 0; sy < S; ++sy) {
                        i64 gib = (i64)(e * S + sy) * 3 * D + cc;
                        float rr = sigf(bf2f(gi[gib]) + hr);
                        float zz = sigf(bf2f(gi[gib + D]) + hz);
                        float nn = tanhfast(bf2f(gi[gib + 2 * D]) + rr * hn2);
                        hy[((i64)mm * S + sy) * D + cc] = f2bf((1.f - zz) * nn + zz * ho[r]);
                    }
                }
            }
        }
    }
}

// ---------------------------------------------------------------- host
extern "C" void kernel_launch(void* const* d_in, const int* in_sizes, int n_in,
                              void* d_out, int out_size, void* d_ws, size_t ws_size,
                              hipStream_t stream) {
    const float* x      = (const float*)d_in[0];
    const float* W_emb0 = (const float*)d_in[1];
    const float* b_emb0 = (const float*)d_in[2];
    const float* Wih0   = (const float*)d_in[3];
    const float* Whh0   = (const float*)d_in[4];
    const float* bih0   = (const float*)d_in[5];
    const float* bhh0   = (const float*)d_in[6];
    const float* Wpred0 = (const float*)d_in[7];
    const float* bpred0 = (const float*)d_in[8];
    const float* pos0   = (const float*)d_in[9];
    const float* chan0  = (const float*)d_in[10];
    const float* W_emb1 = (const float*)d_in[11];
    const float* b_emb1 = (const float*)d_in[12];
    const float* Wih1   = (const float*)d_in[13];
    const float* Whh1   = (const float*)d_in[14];
    const float* bih1   = (const float*)d_in[15];
    const float* bhh1   = (const float*)d_in[16];
    const float* Wpred1 = (const float*)d_in[17];
    const float* bpred1 = (const float*)d_in[18];
    const float* pos1   = (const float*)d_in[19];
    const float* chan1  = (const float*)d_in[20];
    float* out = (float*)d_out;

    i64 off = 0;
    char* base = (char*)d_ws;
    auto alloc = [&](i64 bytes) -> void* {
        void* p = base + off; off += (bytes + 255) & ~(i64)255; return p;
    };
    float* f_hfrag = (float*)alloc((i64)MP * 512 * 4);   // fp32 fragment h-master
    u16*   f_mirA  = (u16*)  alloc((i64)MP * 512 * 2);   // ping-pong row-major mirrors
    u16*   f_mirB  = (u16*)  alloc((i64)MP * 512 * 2);
    u16*   wih0b   = (u16*)  alloc((i64)1536 * 512 * 2);
    u16*   whh0b   = (u16*)  alloc((i64)1536 * 512 * 2);
    u16*   wih1b   = (u16*)  alloc((i64)768 * 256 * 2);
    u16*   whh1b   = (u16*)  alloc((i64)768 * 256 * 2);
    u16*   we0b    = (u16*)  alloc((i64)512 * 64 * 2);
    u16*   we1b    = (u16*)  alloc((i64)256 * 64 * 2);
    u16*   wp0b    = (u16*)  alloc((i64)128 * 512 * 2);
    u16*   wp1b    = (u16*)  alloc((i64)128 * 256 * 2);
    u16*   f_pm0   = (u16*)  alloc((i64)768 * 512 * 2);
    u16*   f_pm1   = (u16*)  alloc((i64)1408 * 256 * 2);
    u16*   f_gidec = (u16*)  alloc((i64)768 * 1536 * 2);
    float* f_y0    = (float*)alloc((i64)NB * 96 * 4);
    float* f_y1    = (float*)alloc((i64)NB * 96 * 4);
    i64 fixed = off;

    char* R = base + fixed;
    i64 a1 = (((i64)4 * MP * 64 * 2) + 255) & ~(i64)255;
    i64 a2 = (((i64)4 * MP * 256 * 2) + 255) & ~(i64)255;
    i64 a3 = (i64)4 * MP * 768 * 2;
    i64 R1 = a1 + a2 + a3;
    u16* f_seg1 = (u16*)R;
    u16* f_xe1  = (u16*)(R + a1);
    u16* f_gi1  = (u16*)(R + a1 + a2);   // fragment-packed, 4 segments
    u16* f_hy   = f_gi1;                  // alias (decoders run after gi use)
    int gsz = 2;
    {
        const int cand[3] = {15, 5, 3};
        for (int ii = 0; ii < 3; ++ii) {
            i64 need = (i64)cand[ii] * MP * (64 + 512 + 1536) * 2 + 3 * 256;
            i64 tot = fixed + (need > R1 ? need : R1);
            if (tot <= (i64)ws_size) { gsz = cand[ii]; break; }
        }
    }
    u16* f_seg0 = (u16*)R;
    i64 s1 = (((i64)gsz * MP * 64 * 2) + 255) & ~(i64)255;
    i64 s2 = (((i64)gsz * MP * 512 * 2) + 255) & ~(i64)255;
    u16* f_xe0 = (u16*)(R + s1);
    u16* f_gi0 = (u16*)(R + s1 + s2);    // fragment-packed, gsz steps

    auto cvt = [&](const float* s, u16* dst, int Rr, int C, int Rp, int Cp) {
        i64 tot = (i64)Rp * Cp;
        convert_pad<<<(int)((tot + 255) / 256), 256, 0, stream>>>(s, dst, Rr, C, Rp, Cp);
    };
    auto gemmN = [&](const u16* A, const u16* B, const float* bias, void* C,
                     int gx, int Nc, int K, int Mstore, int ldc, int mode, int dgate) {
        int NYT = (Nc + 127) / 128;
        dim3 g(gx * NYT);
        if (mode == 0)      gemm_bf16mfma<0><<<g, 256, 0, stream>>>(A, B, bias, C, K, Mstore, Nc, ldc, dgate, gx, NYT);
        else if (mode == 1) gemm_bf16mfma<1><<<g, 256, 0, stream>>>(A, B, bias, C, K, Mstore, Nc, ldc, dgate, gx, NYT);
        else if (mode == 2) gemm_bf16mfma<2><<<g, 256, 0, stream>>>(A, B, bias, C, K, Mstore, Nc, ldc, dgate, gx, NYT);
        else                gemm_bf16mfma<3><<<g, 256, 0, stream>>>(A, B, bias, C, K, Mstore, Nc, ldc, dgate, gx, NYT);
    };

    cvt(Wih0, wih0b, 1536, 512, 1536, 512);
    cvt(Whh0, whh0b, 1536, 512, 1536, 512);
    cvt(Wih1, wih1b, 768, 256, 768, 256);
    cvt(Whh1, whh1b, 768, 256, 768, 256);
    cvt(W_emb0, we0b, 512, 48, 512, 64);
    cvt(W_emb1, we1b, 256, 24, 256, 64);
    cvt(Wpred0, wp0b, 48, 512, 128, 512);
    cvt(Wpred1, wp1b, 24, 256, 128, 256);
    pmat_fill_bf<<<(int)(((i64)768 * 512 + 255) / 256), 256, 0, stream>>>(pos0, chan0, f_pm0, 2, 512, 768);
    pmat_fill_bf<<<(int)(((i64)1408 * 256 + 255) / 256), 256, 0, stream>>>(pos1, chan1, f_pm1, 4, 256, 1408);

    // ================= layer 0: d=512, s=48, 15 steps in groups of gsz ========
    {
        i64 n = (i64)MP * 512;
        zero2_kernel<<<(int)((n + 255) / 256), 256, 0, stream>>>(f_hfrag, f_mirA, n);
    }
    for (int t0 = 0; t0 < 15;) {
        int g = 15 - t0 < gsz ? 15 - t0 : gsz;
        i64 tot = (i64)g * MP * 64;
        seg_gather_bf<<<(int)((tot + 255) / 256), 256, 0, stream>>>(x, f_seg0, t0, g, 48, 64);
        gemmN(f_seg0, we0b, b_emb0, f_xe0, g * 81, 512, 64, g * MP, 512, 2, 0);
        gemmN(f_xe0, wih0b, bih0, f_gi0, g * 81, 1536, 512, 0, 0, 3, 512);   // packed gi
        for (int s = 0; s < g; ++s) {
            int tg = t0 + s;
            const u16* Asrc = (tg & 1) ? f_mirB : f_mirA;
            u16* Adst = (tg & 1) ? f_mirA : f_mirB;
            gru_fused_v2<512, 0><<<dim3(81 * 8), 256, 0, stream>>>(
                Asrc, whh0b, bhh0, f_gi0 + (i64)s * MP * 1536,
                (f32x4*)f_hfrag, Adst, nullptr);
        }
        t0 += g;
    }
    // decoder 0 (15 steps: t=14 wrote mirB)
    gemmN(f_pm0, wih0b, bih0, f_gidec, 6, 1536, 512, 642, 1536, 1, 0);
    gru_fused_v2<512, 2><<<dim3(81 * 8), 256, 0, stream>>>(
        f_mirB, whh0b, bhh0, f_gidec, (f32x4*)f_hfrag, nullptr, f_hy);
    gemmN(f_hy, wp0b, bpred0, f_y0, 161, 48, 512, 2 * NB, 48, 0, 0);

    // ================= layer 1: d=256, s=24, 60 steps (4 gi segments) =========
    {
        i64 n = (i64)MP * 256;
        zero2_kernel<<<(int)((n + 255) / 256), 256, 0, stream>>>(f_hfrag, f_mirA, n);
    }
    {
        i64 tot = (i64)4 * MP * 64;
        seg_gather_bf<<<(int)((tot + 255) / 256), 256, 0, stream>>>(x, f_seg1, 0, 4, 24, 64);
    }
    gemmN(f_seg1, we1b, b_emb1, f_xe1, 324, 256, 64, 4 * MP, 256, 2, 0);
    gemmN(f_xe1, wih1b, bih1, f_gi1, 324, 768, 256, 0, 0, 3, 256);           // packed gi
    for (int t = 0; t < 60; ++t) {
        const u16* Asrc = (t & 1) ? f_mirB : f_mirA;
        u16* Adst = (t & 1) ? f_mirA : f_mirB;
        gru_fused_v2<256, 0><<<dim3(81 * 4), 256, 0, stream>>>(
            Asrc, whh1b, bhh1, f_gi1 + (i64)(t & 3) * MP * 768,
            (f32x4*)f_hfrag, Adst, nullptr);
    }
    // decoder 1 (60 steps: t=59 wrote mirA)
    gemmN(f_pm1, wih1b, bih1, f_gidec, 11, 768, 256, 1284, 768, 1, 0);
    gru_fused_v2<256, 4><<<dim3(81 * 4), 256, 0, stream>>>(
        f_mirA, whh1b, bhh1, f_gidec, (f32x4*)f_hfrag, nullptr, f_hy);
    gemmN(f_hy, wp1b, bpred1, f_y1, 321, 24, 256, 4 * NB, 24, 0, 0);

    // ================= combine =================
    out_kernel<<<(BATCH_ * PRED_ * ENC_ + 255) / 256, 256, 0, stream>>>(x, f_y0, f_y1, out);
}

// Round 8
// 2480.668 us; speedup vs baseline: 4.2566x; 1.1680x over previous
//
#include <hip/hip_runtime.h>
#include <math.h>

// Hierarchical RNN — round 8: concat-K fused encoder step (xe·Wih and h·Whh
// accumulated in one kernel; r,z share accumulators, n keeps i_n/h_n split)
// + 64-row step blocks for ~2x co-residency. gi buffers eliminated.

#define NB     10272
#define MP     10368
#define ENC_   321
#define SEQ_   720
#define PRED_  96
#define BATCH_ 32

typedef long long i64;
typedef unsigned short u16;
typedef unsigned int u32;
using bf16x8 = __attribute__((ext_vector_type(8))) short;
using f32x4  = __attribute__((ext_vector_type(4))) float;

#define AS1 __attribute__((address_space(1)))
#define AS3 __attribute__((address_space(3)))
#define GLOAD16(g, l) __builtin_amdgcn_global_load_lds((const AS1 void*)(g), (AS3 void*)(l), 16, 0, 0)

__device__ __forceinline__ float bf2f(u16 u) {
    union { u32 i; float f; } v; v.i = ((u32)u) << 16; return v.f;
}
__device__ __forceinline__ u16 f2bf(float f) {
    union { float f; u32 i; } v; v.f = f;
    return (u16)((v.i + 0x7fff + ((v.i >> 16) & 1)) >> 16);
}
__device__ __forceinline__ float sigf(float x) {
    x = fminf(fmaxf(x, -30.f), 30.f);
    return 1.f / (1.f + __expf(-x));
}
__device__ __forceinline__ float tanhfast(float x) {
    x = fminf(fmaxf(x, -15.f), 15.f);
    float e = __expf(2.f * x);
    return (e - 1.f) / (e + 1.f);
}
__device__ __forceinline__ float bsel(uint2 u, int r) {
    u32 wv = (r & 2) ? u.y : u.x;
    return bf2f((u16)((r & 1) ? (wv >> 16) : (wv & 0xffff)));
}
// XCD-aware flat-grid swizzle for the big GEMMs
__device__ __forceinline__ void swz(int idx, int NXT, int NYT, int& mt, int& nt) {
    int per = NYT * 8;
    int grp = idx / per;
    int base = grp * 8;
    int mg = NXT - base; if (mg > 8) mg = 8;
    int rem = idx - grp * per;
    mt = base + rem % mg;
    nt = rem / mg;
}

// ---------------------------------------------------------------- small utils
__global__ __launch_bounds__(256) void zero2_kernel(float* __restrict__ a,
                                                    u16* __restrict__ b, i64 n) {
    i64 i = (i64)blockIdx.x * 256 + threadIdx.x;
    if (i < n) { a[i] = 0.f; b[i] = 0; }
}

__global__ __launch_bounds__(256) void convert_pad(const float* __restrict__ src,
                                                   u16* __restrict__ dst,
                                                   int R, int C, int Rp, int Cp) {
    i64 idx = (i64)blockIdx.x * 256 + threadIdx.x;
    i64 total = (i64)Rp * Cp;
    if (idx >= total) return;
    int r = (int)(idx / Cp);
    int c = (int)(idx - (i64)r * Cp);
    dst[idx] = (r < R && c < C) ? f2bf(src[(i64)r * C + c]) : (u16)0;
}

__global__ __launch_bounds__(256) void seg_gather_bf(const float* __restrict__ x,
                                                     u16* __restrict__ dst,
                                                     int t0, int T, int s, int Kp) {
    i64 idx = (i64)blockIdx.x * 256 + threadIdx.x;
    i64 per_t = (i64)MP * Kp;
    i64 total = (i64)T * per_t;
    if (idx >= total) return;
    int t = (int)(idx / per_t);
    i64 rem = idx - (i64)t * per_t;
    int j = (int)(rem / MP);
    int n = (int)(rem - (i64)j * MP);
    float v = 0.f;
    if (n < NB && j < s) {
        int b = n / ENC_, e = n - b * ENC_;
        const float* xb = x + (i64)b * SEQ_ * ENC_ + e;
        v = xb[(i64)((t0 + t) * s + j) * ENC_] - xb[(i64)(SEQ_ - 1) * ENC_];
    }
    dst[((i64)t * MP + n) * Kp + j] = f2bf(v);
}

__global__ __launch_bounds__(256) void pmat_fill_bf(const float* __restrict__ pos,
                                                    const float* __restrict__ chan,
                                                    u16* __restrict__ dst,
                                                    int S, int d, int Rp) {
    i64 idx = (i64)blockIdx.x * 256 + threadIdx.x;
    i64 total = (i64)Rp * d;
    if (idx >= total) return;
    int row = (int)(idx / d);
    int c = (int)(idx - (i64)row * d);
    float v = 0.f;
    if (row < ENC_ * S) {
        int e = row / S, sy = row - e * S;
        int half = d >> 1;
        v = (c < half) ? pos[sy * half + c] : chan[e * half + (c - half)];
    }
    dst[idx] = f2bf(v);
}

__global__ __launch_bounds__(256) void out_kernel(const float* __restrict__ x,
                                                  const float* __restrict__ y0,
                                                  const float* __restrict__ y1,
                                                  float* __restrict__ out) {
    int idx = blockIdx.x * 256 + threadIdx.x;
    const int total = BATCH_ * PRED_ * ENC_;
    if (idx >= total) return;
    int b = idx / (PRED_ * ENC_);
    int r = idx - b * (PRED_ * ENC_);
    int p = r / ENC_;
    int e = r - p * ENC_;
    int n = b * ENC_ + e;
    float sl = x[(i64)b * SEQ_ * ENC_ + (i64)(SEQ_ - 1) * ENC_ + e];
    out[idx] = sl + 0.5f * (y0[(i64)n * PRED_ + p] + y1[(i64)n * PRED_ + p]);
}

// ------------------------------------------------- bf16 MFMA NT GEMM 128x128xK
// MODE: 0 fp32 natural, 1 bf16 natural, 2 bf16+relu
template<int MODE>
__global__ __launch_bounds__(256) void gemm_bf16mfma(const u16* __restrict__ A,
                                                     const u16* __restrict__ B,
                                                     const float* __restrict__ bias,
                                                     void* __restrict__ Cp,
                                                     int K, int Mstore, int Nstore,
                                                     int ldc, int NXT, int NYT) {
    __shared__ u16 smA[128 * 64];
    __shared__ u16 smB[128 * 64];
    const int tid = threadIdx.x;
    const int w = tid >> 6, l = tid & 63;
    int mt, nt; swz(blockIdx.x, NXT, NYT, mt, nt);
    const int m0 = mt * 128, n0 = nt * 128;
    const int srow = (l >> 3) & 7, pch = l & 7;
    const int cch = pch ^ srow;
    const u16* ga[4]; const u16* gb[4];
#pragma unroll
    for (int r = 0; r < 4; ++r) {
        int seg = r * 4 + w;
        ga[r] = A + (i64)(m0 + seg * 8 + srow) * K + cch * 8;
        gb[r] = B + (i64)(n0 + seg * 8 + srow) * K + cch * 8;
    }
    f32x4 acc[4][4] = {};
    const int lr = l & 15, lg = l >> 4;
    const int wm = (w >> 1) * 64, wn = (w & 1) * 64;
    for (int kk = 0; kk < K; kk += 64) {
#pragma unroll
        for (int r = 0; r < 4; ++r) { GLOAD16(ga[r], smA + (r * 4 + w) * 512); ga[r] += 64; }
#pragma unroll
        for (int r = 0; r < 4; ++r) { GLOAD16(gb[r], smB + (r * 4 + w) * 512); gb[r] += 64; }
        __syncthreads();
#pragma unroll
        for (int s = 0; s < 2; ++s) {
            const int ph = ((s * 4 + lg) ^ (lr & 7)) * 8;
            bf16x8 av[4], bv[4];
#pragma unroll
            for (int i = 0; i < 4; ++i)
                av[i] = *(const bf16x8*)(smA + (wm + i * 16 + lr) * 64 + ph);
#pragma unroll
            for (int j = 0; j < 4; ++j)
                bv[j] = *(const bf16x8*)(smB + (wn + j * 16 + lr) * 64 + ph);
#pragma unroll
            for (int i = 0; i < 4; ++i)
#pragma unroll
                for (int j = 0; j < 4; ++j)
                    acc[i][j] = __builtin_amdgcn_mfma_f32_16x16x32_bf16(av[i], bv[j], acc[i][j], 0, 0, 0);
        }
        __syncthreads();
    }
#pragma unroll
    for (int i = 0; i < 4; ++i) {
        int mbase = m0 + wm + i * 16 + 4 * lg;
#pragma unroll
        for (int j = 0; j < 4; ++j) {
            int c = n0 + wn + j * 16 + lr;
            if (c >= Nstore) continue;
            float bs = bias[c];
#pragma unroll
            for (int r = 0; r < 4; ++r) {
                int mm = mbase + r;
                if (mm < Mstore) {
                    float v = acc[i][j][r] + bs;
                    if (MODE == 2) v = fmaxf(v, 0.f);
                    if (MODE == 0) ((float*)Cp)[(i64)mm * ldc + c] = v;
                    else           ((u16*)Cp)[(i64)mm * ldc + c] = f2bf(v);
                }
            }
        }
    }
}

// ---------------- concat-K fused encoder step: (xe·Wih + h·Whh) + GRU update
// 64 rows x 64 cols x 3 gates per block; grid (162, D/64).
// r,z accumulate across both phases; n keeps i_n (phase0) / h_n (phase1) split.
// h fp32 master in fragment layout; writes new h to Adst mirror (ping-pong).
template<int D>
__global__ __launch_bounds__(256, 3) void gru_step(const u16* __restrict__ xe,
                                                   const u16* __restrict__ hsrc,
                                                   const u16* __restrict__ Wih,
                                                   const u16* __restrict__ Whh,
                                                   const float* __restrict__ bih,
                                                   const float* __restrict__ bhh,
                                                   f32x4* __restrict__ hfrag,
                                                   u16* __restrict__ hdst) {
    constexpr int NCT = D / 16;
    __shared__ u16 smA[64 * 64];
    __shared__ u16 smB[3 * 64 * 64];
    const int tid = threadIdx.x;
    const int w = tid >> 6, l = tid & 63;
    const int m0 = blockIdx.x * 64;
    const int c0 = blockIdx.y * 64;
    const int srow = (l >> 3) & 7, pch = l & 7;
    const int cch = pch ^ srow;
    const int lr = l & 15, lg = l >> 4;
    f32x4 aR[4] = {}, aZ[4] = {}, aNI[4] = {}, aNH[4] = {};
#pragma unroll
    for (int phase = 0; phase < 2; ++phase) {
        const u16* Abase = phase ? hsrc : xe;
        const u16* Bbase = phase ? Whh : Wih;
        const u16* ga[2]; const u16* gb[6];
#pragma unroll
        for (int r = 0; r < 2; ++r)
            ga[r] = Abase + (i64)(m0 + (r * 4 + w) * 8 + srow) * D + cch * 8;
#pragma unroll
        for (int q = 0; q < 6; ++q) {
            int gs = q * 4 + w;
            int g = gs >> 3, sp = gs & 7;
            gb[q] = Bbase + (i64)(g * D + c0 + sp * 8 + srow) * D + cch * 8;
        }
        for (int kk = 0; kk < D; kk += 64) {
#pragma unroll
            for (int r = 0; r < 2; ++r) { GLOAD16(ga[r], smA + (r * 4 + w) * 512); ga[r] += 64; }
#pragma unroll
            for (int q = 0; q < 6; ++q) { GLOAD16(gb[q], smB + (q * 4 + w) * 512); gb[q] += 64; }
            __syncthreads();
#pragma unroll
            for (int s = 0; s < 2; ++s) {
                const int phs = ((s * 4 + lg) ^ (lr & 7)) * 8;
                bf16x8 av = *(const bf16x8*)(smA + (w * 16 + lr) * 64 + phs);
#pragma unroll
                for (int j = 0; j < 4; ++j) {
                    bf16x8 b0 = *(const bf16x8*)(smB + 0 * 4096 + (j * 16 + lr) * 64 + phs);
                    bf16x8 b1 = *(const bf16x8*)(smB + 1 * 4096 + (j * 16 + lr) * 64 + phs);
                    bf16x8 b2 = *(const bf16x8*)(smB + 2 * 4096 + (j * 16 + lr) * 64 + phs);
                    aR[j] = __builtin_amdgcn_mfma_f32_16x16x32_bf16(av, b0, aR[j], 0, 0, 0);
                    aZ[j] = __builtin_amdgcn_mfma_f32_16x16x32_bf16(av, b1, aZ[j], 0, 0, 0);
                    if (phase == 0)
                        aNI[j] = __builtin_amdgcn_mfma_f32_16x16x32_bf16(av, b2, aNI[j], 0, 0, 0);
                    else
                        aNH[j] = __builtin_amdgcn_mfma_f32_16x16x32_bf16(av, b2, aNH[j], 0, 0, 0);
                }
            }
            __syncthreads();
        }
    }
    // epilogue
    const int Trow = (m0 >> 4) + w;
    const int rowb = m0 + w * 16 + 4 * lg;
#pragma unroll
    for (int j = 0; j < 4; ++j) {
        const int cc = c0 + j * 16 + lr;
        const i64 tb = (i64)Trow * NCT + ((c0 >> 4) + j);
        f32x4 ho = hfrag[tb * 64 + l];
        float bR = bih[cc] + bhh[cc];
        float bZ = bih[D + cc] + bhh[D + cc];
        float bNI = bih[2 * D + cc];
        float bNH = bhh[2 * D + cc];
        f32x4 hn;
#pragma unroll
        for (int r = 0; r < 4; ++r) {
            float rr = sigf(aR[j][r] + bR);
            float zz = sigf(aZ[j][r] + bZ);
            float nn = tanhfast(aNI[j][r] + bNI + rr * (aNH[j][r] + bNH));
            hn[r] = (1.f - zz) * nn + zz * ho[r];
        }
        hfrag[tb * 64 + l] = hn;
#pragma unroll
        for (int r = 0; r < 4; ++r)
            hdst[(i64)(rowb + r) * D + cc] = f2bf(hn[r]);
    }
}

// ---------------------------------------- decoder: fused gh-GEMM + GRU (S>0)
template<int D, int S>
__global__ __launch_bounds__(256) void gru_dec(const u16* __restrict__ Asrc,
                                               const u16* __restrict__ Whh,
                                               const float* __restrict__ bhh,
                                               const u16* __restrict__ gi,
                                               const f32x4* __restrict__ hfrag,
                                               u16* __restrict__ hy) {
    constexpr int NCT = D / 16;
    constexpr int NYT = D / 64;
    __shared__ u16 smA[128 * 64];
    __shared__ u16 smB[3 * 64 * 64];
    const int tid = threadIdx.x;
    const int w = tid >> 6, l = tid & 63;
    int mt, nt; swz(blockIdx.x, 81, NYT, mt, nt);
    const int m0 = mt * 128;
    const int c0 = nt * 64;
    const int srow = (l >> 3) & 7, pch = l & 7;
    const int cch = pch ^ srow;
    const u16* ga[4]; const u16* gb[6];
#pragma unroll
    for (int r = 0; r < 4; ++r)
        ga[r] = Asrc + (i64)(m0 + (r * 4 + w) * 8 + srow) * D + cch * 8;
#pragma unroll
    for (int q = 0; q < 6; ++q) {
        int gs = q * 4 + w;
        int g = gs >> 3, sp = gs & 7;
        gb[q] = Whh + (i64)(g * D + c0 + sp * 8 + srow) * D + cch * 8;
    }
    f32x4 acc[3][4][2] = {};
    const int lr = l & 15, lg = l >> 4;
    const int wm = (w >> 1) * 64, wc = (w & 1) * 32;
    for (int kk = 0; kk < D; kk += 64) {
#pragma unroll
        for (int r = 0; r < 4; ++r) { GLOAD16(ga[r], smA + (r * 4 + w) * 512); ga[r] += 64; }
#pragma unroll
        for (int q = 0; q < 6; ++q) { GLOAD16(gb[q], smB + (q * 4 + w) * 512); gb[q] += 64; }
        __syncthreads();
#pragma unroll
        for (int s = 0; s < 2; ++s) {
            const int ph = ((s * 4 + lg) ^ (lr & 7)) * 8;
            bf16x8 av[4], bv[3][2];
#pragma unroll
            for (int i = 0; i < 4; ++i)
                av[i] = *(const bf16x8*)(smA + (wm + i * 16 + lr) * 64 + ph);
#pragma unroll
            for (int g = 0; g < 3; ++g)
#pragma unroll
                for (int j = 0; j < 2; ++j)
                    bv[g][j] = *(const bf16x8*)(smB + g * 4096 + (wc + j * 16 + lr) * 64 + ph);
#pragma unroll
            for (int g = 0; g < 3; ++g)
#pragma unroll
                for (int i = 0; i < 4; ++i)
#pragma unroll
                    for (int j = 0; j < 2; ++j)
                        acc[g][i][j] = __builtin_amdgcn_mfma_f32_16x16x32_bf16(av[i], bv[g][j], acc[g][i][j], 0, 0, 0);
        }
        __syncthreads();
    }
#pragma unroll
    for (int i = 0; i < 4; ++i) {
        const int Trow = (m0 + wm + 16 * i) >> 4;
        const int rowb = m0 + wm + 16 * i + 4 * lg;
#pragma unroll
        for (int j = 0; j < 2; ++j) {
            const int cc = c0 + wc + 16 * j + lr;
            const int ct = (c0 + wc + 16 * j) >> 4;
            const i64 tb = (i64)Trow * NCT + ct;
            float b0 = bhh[cc], b1 = bhh[D + cc], b2 = bhh[2 * D + cc];
            f32x4 ho = hfrag[tb * 64 + l];
#pragma unroll
            for (int r = 0; r < 4; ++r) {
                int mm = rowb + r;
                if (mm >= NB) continue;
                int e = mm % ENC_;
                float hr = acc[0][i][j][r] + b0;
                float hz = acc[1][i][j][r] + b1;
                float hn2 = acc[2][i][j][r] + b2;
#pragma unroll
                for (int sy = 0; sy < S; ++sy) {
                    i64 gib = (i64)(e * S + sy) * 3 * D + cc;
                    float rr = sigf(bf2f(gi[gib]) + hr);
                    float zz = sigf(bf2f(gi[gib + D]) + hz);
                    float nn = tanhfast(bf2f(gi[gib + 2 * D]) + rr * hn2);
                    hy[((i64)mm * S + sy) * D + cc] = f2bf((1.f - zz) * nn + zz * ho[r]);
                }
            }
        }
    }
}

// ---------------------------------------------------------------- host
extern "C" void kernel_launch(void* const* d_in, const int* in_sizes, int n_in,
                              void* d_out, int out_size, void* d_ws, size_t ws_size,
                              hipStream_t stream) {
    const float* x      = (const float*)d_in[0];
    const float* W_emb0 = (const float*)d_in[1];
    const float* b_emb0 = (const float*)d_in[2];
    const float* Wih0   = (const float*)d_in[3];
    const float* Whh0   = (const float*)d_in[4];
    const float* bih0   = (const float*)d_in[5];
    const float* bhh0   = (const float*)d_in[6];
    const float* Wpred0 = (const float*)d_in[7];
    const float* bpred0 = (const float*)d_in[8];
    const float* pos0   = (const float*)d_in[9];
    const float* chan0  = (const float*)d_in[10];
    const float* W_emb1 = (const float*)d_in[11];
    const float* b_emb1 = (const float*)d_in[12];
    const float* Wih1   = (const float*)d_in[13];
    const float* Whh1   = (const float*)d_in[14];
    const float* bih1   = (const float*)d_in[15];
    const float* bhh1   = (const float*)d_in[16];
    const float* Wpred1 = (const float*)d_in[17];
    const float* bpred1 = (const float*)d_in[18];
    const float* pos1   = (const float*)d_in[19];
    const float* chan1  = (const float*)d_in[20];
    float* out = (float*)d_out;

    i64 off = 0;
    char* base = (char*)d_ws;
    auto alloc = [&](i64 bytes) -> void* {
        void* p = base + off; off += (bytes + 255) & ~(i64)255; return p;
    };
    float* f_hfrag = (float*)alloc((i64)MP * 512 * 4);   // fp32 fragment h-master
    u16*   f_mirA  = (u16*)  alloc((i64)MP * 512 * 2);   // ping-pong mirrors
    u16*   f_mirB  = (u16*)  alloc((i64)MP * 512 * 2);
    u16*   wih0b   = (u16*)  alloc((i64)1536 * 512 * 2);
    u16*   whh0b   = (u16*)  alloc((i64)1536 * 512 * 2);
    u16*   wih1b   = (u16*)  alloc((i64)768 * 256 * 2);
    u16*   whh1b   = (u16*)  alloc((i64)768 * 256 * 2);
    u16*   we0b    = (u16*)  alloc((i64)512 * 64 * 2);
    u16*   we1b    = (u16*)  alloc((i64)256 * 64 * 2);
    u16*   wp0b    = (u16*)  alloc((i64)128 * 512 * 2);
    u16*   wp1b    = (u16*)  alloc((i64)128 * 256 * 2);
    u16*   f_pm0   = (u16*)  alloc((i64)768 * 512 * 2);
    u16*   f_pm1   = (u16*)  alloc((i64)1408 * 256 * 2);
    u16*   f_gidec = (u16*)  alloc((i64)768 * 1536 * 2);
    u16*   f_hy    = (u16*)  alloc((i64)4 * NB * 256 * 2); // decoder hy (max of layers)
    float* f_y0    = (float*)alloc((i64)NB * 96 * 4);
    float* f_y1    = (float*)alloc((i64)NB * 96 * 4);
    i64 fixed = off;

    // shared region R: layer-0 (seg0|xe0 for gsz steps) OR layer-1 (seg1|xe1)
    char* R = base + fixed;
    i64 a1 = (((i64)4 * MP * 64 * 2) + 255) & ~(i64)255;
    i64 a2 = (i64)4 * MP * 256 * 2;
    i64 R1 = a1 + a2;
    u16* f_seg1 = (u16*)R;
    u16* f_xe1  = (u16*)(R + a1);
    int gsz = 1;
    {
        const int cand[4] = {15, 5, 3, 2};
        for (int ii = 0; ii < 4; ++ii) {
            i64 need = (i64)cand[ii] * MP * (64 + 512) * 2 + 2 * 256;
            i64 tot = fixed + (need > R1 ? need : R1);
            if (tot <= (i64)ws_size) { gsz = cand[ii]; break; }
        }
    }
    u16* f_seg0 = (u16*)R;
    i64 s1 = (((i64)gsz * MP * 64 * 2) + 255) & ~(i64)255;
    u16* f_xe0 = (u16*)(R + s1);

    auto cvt = [&](const float* s, u16* dst, int Rr, int C, int Rp, int Cp) {
        i64 tot = (i64)Rp * Cp;
        convert_pad<<<(int)((tot + 255) / 256), 256, 0, stream>>>(s, dst, Rr, C, Rp, Cp);
    };
    auto gemmN = [&](const u16* A, const u16* B, const float* bias, void* C,
                     int gx, int Nc, int K, int Mstore, int ldc, int mode) {
        int NYT = (Nc + 127) / 128;
        dim3 g(gx * NYT);
        if (mode == 0)      gemm_bf16mfma<0><<<g, 256, 0, stream>>>(A, B, bias, C, K, Mstore, Nc, ldc, gx, NYT);
        else if (mode == 1) gemm_bf16mfma<1><<<g, 256, 0, stream>>>(A, B, bias, C, K, Mstore, Nc, ldc, gx, NYT);
        else                gemm_bf16mfma<2><<<g, 256, 0, stream>>>(A, B, bias, C, K, Mstore, Nc, ldc, gx, NYT);
    };

    cvt(Wih0, wih0b, 1536, 512, 1536, 512);
    cvt(Whh0, whh0b, 1536, 512, 1536, 512);
    cvt(Wih1, wih1b, 768, 256, 768, 256);
    cvt(Whh1, whh1b, 768, 256, 768, 256);
    cvt(W_emb0, we0b, 512, 48, 512, 64);
    cvt(W_emb1, we1b, 256, 24, 256, 64);
    cvt(Wpred0, wp0b, 48, 512, 128, 512);
    cvt(Wpred1, wp1b, 24, 256, 128, 256);
    pmat_fill_bf<<<(int)(((i64)768 * 512 + 255) / 256), 256, 0, stream>>>(pos0, chan0, f_pm0, 2, 512, 768);
    pmat_fill_bf<<<(int)(((i64)1408 * 256 + 255) / 256), 256, 0, stream>>>(pos1, chan1, f_pm1, 4, 256, 1408);

    // ================= layer 0: d=512, s=48, 15 steps =================
    {
        i64 n = (i64)MP * 512;
        zero2_kernel<<<(int)((n + 255) / 256), 256, 0, stream>>>(f_hfrag, f_mirA, n);
    }
    for (int t0 = 0; t0 < 15;) {
        int g = 15 - t0 < gsz ? 15 - t0 : gsz;
        i64 tot = (i64)g * MP * 64;
        seg_gather_bf<<<(int)((tot + 255) / 256), 256, 0, stream>>>(x, f_seg0, t0, g, 48, 64);
        gemmN(f_seg0, we0b, b_emb0, f_xe0, g * 81, 512, 64, g * MP, 512, 2);
        for (int s = 0; s < g; ++s) {
            int tg = t0 + s;
            const u16* Asrc = (tg & 1) ? f_mirB : f_mirA;
            u16* Adst = (tg & 1) ? f_mirA : f_mirB;
            gru_step<512><<<dim3(162, 8), 256, 0, stream>>>(
                f_xe0 + (i64)s * MP * 512, Asrc, wih0b, whh0b, bih0, bhh0,
                (f32x4*)f_hfrag, Adst);
        }
        t0 += g;
    }
    // decoder 0 (t=14 wrote mirB)
    gemmN(f_pm0, wih0b, bih0, f_gidec, 6, 1536, 512, 642, 1536, 1);
    gru_dec<512, 2><<<dim3(81 * 8), 256, 0, stream>>>(
        f_mirB, whh0b, bhh0, f_gidec, (const f32x4*)f_hfrag, f_hy);
    gemmN(f_hy, wp0b, bpred0, f_y0, 161, 48, 512, 2 * NB, 48, 0);

    // ================= layer 1: d=256, s=24, 60 steps (4 xe segments) =========
    {
        i64 n = (i64)MP * 256;
        zero2_kernel<<<(int)((n + 255) / 256), 256, 0, stream>>>(f_hfrag, f_mirA, n);
    }
    {
        i64 tot = (i64)4 * MP * 64;
        seg_gather_bf<<<(int)((tot + 255) / 256), 256, 0, stream>>>(x, f_seg1, 0, 4, 24, 64);
    }
    gemmN(f_seg1, we1b, b_emb1, f_xe1, 324, 256, 64, 4 * MP, 256, 2);
    for (int t = 0; t < 60; ++t) {
        const u16* Asrc = (t & 1) ? f_mirB : f_mirA;
        u16* Adst = (t & 1) ? f_mirA : f_mirB;
        gru_step<256><<<dim3(162, 4), 256, 0, stream>>>(
            f_xe1 + (i64)(t & 3) * MP * 256, Asrc, wih1b, whh1b, bih1, bhh1,
            (f32x4*)f_hfrag, Adst);
    }
    // decoder 1 (t=59 wrote mirA)
    gemmN(f_pm1, wih1b, bih1, f_gidec, 11, 768, 256, 1284, 768, 1);
    gru_dec<256, 4><<<dim3(81 * 4), 256, 0, stream>>>(
        f_mirA, whh1b, bhh1, f_gidec, (const f32x4*)f_hfrag, f_hy);
    gemmN(f_hy, wp1b, bpred1, f_y1, 321, 24, 256, 4 * NB, 24, 0);

    // ================= combine =================
    out_kernel<<<(BATCH_ * PRED_ * ENC_ + 255) / 256, 256, 0, stream>>>(x, f_y0, f_y1, out);
}